// Round 1
// baseline (332.685 us; speedup 1.0000x reference)
//
#include <hip/hip_runtime.h>

#define VOCAB 128
#define EMB   8
#define HID   32
#define BATCH 512
#define SEQ   512
#define G4    128   // 4*HID

// ---------------------------------------------------------------------------
// Kernel 1: proj[v][r] = dot(emb[v], w_ih[r]) + b_ih[r] + b_hh[r]
// 128 tokens x 128 gate-rows, tiny.
// ---------------------------------------------------------------------------
__global__ void build_proj(const float* __restrict__ emb,
                           const float* __restrict__ w_ih,
                           const float* __restrict__ b_ih,
                           const float* __restrict__ b_hh,
                           float* __restrict__ proj) {
    int idx = blockIdx.x * blockDim.x + threadIdx.x;   // 0 .. 16383
    int v = idx >> 7;
    int r = idx & 127;
    float acc = b_ih[r] + b_hh[r];
#pragma unroll
    for (int e = 0; e < EMB; ++e)
        acc += emb[v * EMB + e] * w_ih[r * EMB + e];
    proj[v * G4 + r] = acc;
}

// ---------------------------------------------------------------------------
// Kernel 2: LSTM recurrence. One wave (64 lanes) per batch sequence.
// Lane l owns gate rows l and l+64. h[j] broadcast via v_readlane -> SGPR.
// ---------------------------------------------------------------------------
__device__ __forceinline__ float sigmoid_fast(float x) {
    return 1.0f / (1.0f + __expf(-x));
}
__device__ __forceinline__ float tanh_fast(float x) {
    // stable at both extremes: exp(2x)->inf => 1, ->0 => -1
    return 1.0f - 2.0f / (__expf(2.0f * x) + 1.0f);
}

__global__ __launch_bounds__(64, 1) void lstm_rec(
    const int*   __restrict__ tokens,   // [B][T]
    const float* __restrict__ w_hh,     // [128][32]
    const float* __restrict__ proj,     // [128][128]
    float*       __restrict__ h_out)    // [B*T][32]
{
    const int b    = blockIdx.x;
    const int lane = threadIdx.x;      // 0..63
    const bool lo  = (lane < 32);

    // Preload recurrent weight rows for this lane's two gate rows.
    float w0[HID], w1[HID];
#pragma unroll
    for (int j = 0; j < HID; ++j) {
        w0[j] = w_hh[lane * HID + j];
        w1[j] = w_hh[(lane + 64) * HID + j];
    }

    const int* tok = tokens + b * SEQ;

    float h = 0.0f, c = 0.0f;

    // Prefetch pipeline: xp for step t loaded during step t-1; token for
    // step t+1 loaded during step t-1 as well.
    int tnext = tok[0];
    float xp0 = proj[tnext * G4 + lane];
    float xp1 = proj[tnext * G4 + 64 + lane];
    tnext = tok[1];

    float* hp = h_out + (size_t)b * SEQ * HID + lane;   // lanes<32 store

    for (int t = 0; t < SEQ; ++t) {
        // two partial chains per accumulator for ILP
        float a0a = xp0, a1a = xp1;
        float a0b = 0.0f, a1b = 0.0f;

        // issue next-step prefetch early
        float nxp0 = proj[tnext * G4 + lane];
        float nxp1 = proj[tnext * G4 + 64 + lane];
        tnext = tok[(t + 2 < SEQ) ? (t + 2) : 0];

        unsigned hbits = __float_as_uint(h);
#pragma unroll
        for (int j = 0; j < HID; j += 2) {
            float hj0 = __uint_as_float(__builtin_amdgcn_readlane(hbits, j));
            float hj1 = __uint_as_float(__builtin_amdgcn_readlane(hbits, j + 1));
            a0a = fmaf(hj0, w0[j],     a0a);
            a1a = fmaf(hj0, w1[j],     a1a);
            a0b = fmaf(hj1, w0[j + 1], a0b);
            a1b = fmaf(hj1, w1[j + 1], a1b);
        }
        float acc0 = a0a + a0b;   // row lane      : i[l] (lo) / f[l-32] (hi)
        float acc1 = a1a + a1b;   // row lane+64   : g[l] (lo) / o[l-32] (hi)

        float p0 = __shfl_xor(acc0, 32);
        float p1 = __shfl_xor(acc1, 32);

        float iv = lo ? acc0 : p0;
        float fv = lo ? p0 : acc0;
        float gv = lo ? acc1 : p1;
        float ov = lo ? p1 : acc1;

        c = sigmoid_fast(fv) * c + sigmoid_fast(iv) * tanh_fast(gv);
        h = sigmoid_fast(ov) * tanh_fast(c);

        if (lo) hp[(size_t)t * HID] = h;

        xp0 = nxp0;
        xp1 = nxp1;
    }
}

// ---------------------------------------------------------------------------
// Kernel 3: logits[pos][v] = h[pos] . w_out[v] + b_out[v]
// Wave handles POS_PER_WAVE consecutive positions; lane covers vocab v=lane
// and v=lane+64. h reads are wave-uniform (scalar path via readfirstlane).
// ---------------------------------------------------------------------------
#define POS_PER_WAVE 16

__global__ __launch_bounds__(256) void out_proj(
    const float* __restrict__ h,      // [B*T][32]
    const float* __restrict__ w_out,  // [128][32]
    const float* __restrict__ b_out,  // [128]
    float*       __restrict__ out)    // [B*T][128]
{
    const int gtid = blockIdx.x * blockDim.x + threadIdx.x;
    const int wave = gtid >> 6;
    const int lane = threadIdx.x & 63;

    float wv0[HID], wv1[HID];
#pragma unroll
    for (int j = 0; j < HID; ++j) {
        wv0[j] = w_out[lane * HID + j];
        wv1[j] = w_out[(lane + 64) * HID + j];
    }
    const float bb0 = b_out[lane];
    const float bb1 = b_out[lane + 64];

    int pos0 = wave * POS_PER_WAVE;
    for (int p = 0; p < POS_PER_WAVE; ++p) {
        int pos = __builtin_amdgcn_readfirstlane(pos0 + p);
        const float* hp = h + (size_t)pos * HID;
        float a0 = bb0, a1 = bb1;
#pragma unroll
        for (int j4 = 0; j4 < HID / 4; ++j4) {
            float4 hv = *reinterpret_cast<const float4*>(hp + 4 * j4);
            a0 = fmaf(hv.x, wv0[4 * j4 + 0], a0);
            a1 = fmaf(hv.x, wv1[4 * j4 + 0], a1);
            a0 = fmaf(hv.y, wv0[4 * j4 + 1], a0);
            a1 = fmaf(hv.y, wv1[4 * j4 + 1], a1);
            a0 = fmaf(hv.z, wv0[4 * j4 + 2], a0);
            a1 = fmaf(hv.z, wv1[4 * j4 + 2], a1);
            a0 = fmaf(hv.w, wv0[4 * j4 + 3], a0);
            a1 = fmaf(hv.w, wv1[4 * j4 + 3], a1);
        }
        out[(size_t)pos * VOCAB + lane]      = a0;
        out[(size_t)pos * VOCAB + 64 + lane] = a1;
    }
}

// ---------------------------------------------------------------------------
extern "C" void kernel_launch(void* const* d_in, const int* in_sizes, int n_in,
                              void* d_out, int out_size, void* d_ws, size_t ws_size,
                              hipStream_t stream) {
    const int*   tokens = (const int*)  d_in[0];
    const float* emb    = (const float*)d_in[1];
    const float* w_ih   = (const float*)d_in[2];
    const float* w_hh   = (const float*)d_in[3];
    const float* b_ih   = (const float*)d_in[4];
    const float* b_hh   = (const float*)d_in[5];
    const float* w_out  = (const float*)d_in[6];
    const float* b_out  = (const float*)d_in[7];
    float*       out    = (float*)d_out;

    // workspace layout: proj table (64 KB) | h buffer (B*T*H f32 = 33.5 MB)
    float* proj = (float*)d_ws;
    float* hbuf = (float*)((char*)d_ws + VOCAB * G4 * sizeof(float));

    // K1: token -> gate-preactivation table
    build_proj<<<(VOCAB * G4) / 256, 256, 0, stream>>>(emb, w_ih, b_ih, b_hh, proj);

    // K2: recurrence, one wave per batch
    lstm_rec<<<BATCH, 64, 0, stream>>>(tokens, w_hh, proj, hbuf);

    // K3: output projection
    const int total_pos = BATCH * SEQ;                    // 262144
    const int waves     = total_pos / POS_PER_WAVE;       // 16384
    out_proj<<<waves / 4, 256, 0, stream>>>(hbuf, w_out, b_out, out);
}

// Round 2
// 246.477 us; speedup vs baseline: 1.3498x; 1.3498x over previous
//
#include <hip/hip_runtime.h>

#define VOCAB 128
#define EMB   8
#define HID   32
#define BATCH 512
#define SEQ   512
#define G4    128   // 4*HID

// ---------------------------------------------------------------------------
// Kernel 1: proj[v][r] = dot(emb[v], w_ih[r]) + b_ih[r] + b_hh[r]
// ---------------------------------------------------------------------------
__global__ void build_proj(const float* __restrict__ emb,
                           const float* __restrict__ w_ih,
                           const float* __restrict__ b_ih,
                           const float* __restrict__ b_hh,
                           float* __restrict__ proj) {
    int idx = blockIdx.x * blockDim.x + threadIdx.x;   // 0 .. 16383
    int v = idx >> 7;
    int r = idx & 127;
    float acc = b_ih[r] + b_hh[r];
#pragma unroll
    for (int e = 0; e < EMB; ++e)
        acc += emb[v * EMB + e] * w_ih[r * EMB + e];
    proj[v * G4 + r] = acc;
}

// ---------------------------------------------------------------------------
// Kernel 2: LSTM recurrence. One wave per batch sequence.
// Lane l owns gate rows l and l+64. h broadcast via v_readlane.
// Gate halves exchanged with v_permlane32_swap_b32 (VALU) instead of
// ds_bpermute. h stores batched x16 to keep vmcnt off the critical path.
// ---------------------------------------------------------------------------
__device__ __forceinline__ float sigmoid_fast(float x) {
    return 1.0f / (1.0f + __expf(-x));
}
__device__ __forceinline__ float tanh_fast(float x) {
    return 1.0f - 2.0f / (__expf(2.0f * x) + 1.0f);
}

__global__ __launch_bounds__(64, 1) void lstm_rec(
    const int*   __restrict__ tokens,   // [B][T]
    const float* __restrict__ w_hh,     // [128][32]
    const float* __restrict__ proj,     // [128][128]
    float*       __restrict__ h_out)    // [B*T][32]
{
    const int b    = blockIdx.x;
    const int lane = threadIdx.x;      // 0..63

    // Recurrent weight rows for this lane's two gate rows.
    float w0[HID], w1[HID];
#pragma unroll
    for (int j = 0; j < HID; ++j) {
        w0[j] = w_hh[lane * HID + j];
        w1[j] = w_hh[(lane + 64) * HID + j];
    }

    const int* tok = tokens + b * SEQ;

    float h = 0.0f, c = 0.0f;

    // Software pipeline: xp loads kept 2 steps ahead.
    int ta = tok[0];
    int tb = tok[1];
    float xa0 = proj[ta * G4 + lane],      xa1 = proj[ta * G4 + 64 + lane];
    float xb0 = proj[tb * G4 + lane],      xb1 = proj[tb * G4 + 64 + lane];
    int tnext = tok[2];

    float* hp = h_out + (size_t)b * SEQ * HID + lane;   // lanes<32 store

    float hsave[16];

    for (int t0 = 0; t0 < SEQ; t0 += 16) {
#pragma unroll
        for (int k = 0; k < 16; ++k) {
            const int t = t0 + k;

            // issue prefetch for step t+2
            float nx0 = proj[tnext * G4 + lane];
            float nx1 = proj[tnext * G4 + 64 + lane];
            int t3 = t + 3;
            tnext = tok[t3 < SEQ ? t3 : 0];

            // matvec: 8 independent chains of depth 8
            float s0 = xa0, s1 = 0.0f, s2 = 0.0f, s3 = 0.0f;  // row lane
            float u0 = xa1, u1 = 0.0f, u2 = 0.0f, u3 = 0.0f;  // row lane+64
            unsigned hb = __float_as_uint(h);
#pragma unroll
            for (int j = 0; j < HID; j += 4) {
                float h0 = __uint_as_float(__builtin_amdgcn_readlane(hb, j));
                float h1 = __uint_as_float(__builtin_amdgcn_readlane(hb, j + 1));
                float h2 = __uint_as_float(__builtin_amdgcn_readlane(hb, j + 2));
                float h3 = __uint_as_float(__builtin_amdgcn_readlane(hb, j + 3));
                s0 = fmaf(h0, w0[j],     s0);
                s1 = fmaf(h1, w0[j + 1], s1);
                s2 = fmaf(h2, w0[j + 2], s2);
                s3 = fmaf(h3, w0[j + 3], s3);
                u0 = fmaf(h0, w1[j],     u0);
                u1 = fmaf(h1, w1[j + 1], u1);
                u2 = fmaf(h2, w1[j + 2], u2);
                u3 = fmaf(h3, w1[j + 3], u3);
            }
            float acc0 = (s0 + s1) + (s2 + s3);  // i (lo lanes) | f (hi lanes)
            float acc1 = (u0 + u1) + (u2 + u3);  // g (lo lanes) | o (hi lanes)

            // broadcast both halves to all lanes: after swap,
            // iv = lo-half everywhere, fv = hi-half everywhere.
            float iv = acc0, fv = acc0;
            asm("v_permlane32_swap_b32 %0, %1" : "+v"(iv), "+v"(fv));
            float gv = acc1, ov = acc1;
            asm("v_permlane32_swap_b32 %0, %1" : "+v"(gv), "+v"(ov));

            c = sigmoid_fast(fv) * c + sigmoid_fast(iv) * tanh_fast(gv);
            h = sigmoid_fast(ov) * tanh_fast(c);
            hsave[k] = h;

            xa0 = xb0; xa1 = xb1;
            xb0 = nx0; xb1 = nx1;
        }
        // batched store flush: one vmcnt high-water every 16 steps
        if (lane < 32) {
#pragma unroll
            for (int k = 0; k < 16; ++k)
                hp[(size_t)(t0 + k) * HID] = hsave[k];
        }
    }
}

// ---------------------------------------------------------------------------
// Kernel 3: logits[pos][v] = h[pos] . w_out[v] + b_out[v]
// ---------------------------------------------------------------------------
#define POS_PER_WAVE 16

__global__ __launch_bounds__(256) void out_proj(
    const float* __restrict__ h,      // [B*T][32]
    const float* __restrict__ w_out,  // [128][32]
    const float* __restrict__ b_out,  // [128]
    float*       __restrict__ out)    // [B*T][128]
{
    const int gtid = blockIdx.x * blockDim.x + threadIdx.x;
    const int wave = gtid >> 6;
    const int lane = threadIdx.x & 63;

    float wv0[HID], wv1[HID];
#pragma unroll
    for (int j = 0; j < HID; ++j) {
        wv0[j] = w_out[lane * HID + j];
        wv1[j] = w_out[(lane + 64) * HID + j];
    }
    const float bb0 = b_out[lane];
    const float bb1 = b_out[lane + 64];

    int pos0 = wave * POS_PER_WAVE;
    for (int p = 0; p < POS_PER_WAVE; ++p) {
        int pos = __builtin_amdgcn_readfirstlane(pos0 + p);
        const float* hp = h + (size_t)pos * HID;
        float a0 = bb0, a1 = bb1;
#pragma unroll
        for (int j4 = 0; j4 < HID / 4; ++j4) {
            float4 hv = *reinterpret_cast<const float4*>(hp + 4 * j4);
            a0 = fmaf(hv.x, wv0[4 * j4 + 0], a0);
            a1 = fmaf(hv.x, wv1[4 * j4 + 0], a1);
            a0 = fmaf(hv.y, wv0[4 * j4 + 1], a0);
            a1 = fmaf(hv.y, wv1[4 * j4 + 1], a1);
            a0 = fmaf(hv.z, wv0[4 * j4 + 2], a0);
            a1 = fmaf(hv.z, wv1[4 * j4 + 2], a1);
            a0 = fmaf(hv.w, wv0[4 * j4 + 3], a0);
            a1 = fmaf(hv.w, wv1[4 * j4 + 3], a1);
        }
        out[(size_t)pos * VOCAB + lane]      = a0;
        out[(size_t)pos * VOCAB + 64 + lane] = a1;
    }
}

// ---------------------------------------------------------------------------
extern "C" void kernel_launch(void* const* d_in, const int* in_sizes, int n_in,
                              void* d_out, int out_size, void* d_ws, size_t ws_size,
                              hipStream_t stream) {
    const int*   tokens = (const int*)  d_in[0];
    const float* emb    = (const float*)d_in[1];
    const float* w_ih   = (const float*)d_in[2];
    const float* w_hh   = (const float*)d_in[3];
    const float* b_ih   = (const float*)d_in[4];
    const float* b_hh   = (const float*)d_in[5];
    const float* w_out  = (const float*)d_in[6];
    const float* b_out  = (const float*)d_in[7];
    float*       out    = (float*)d_out;

    float* proj = (float*)d_ws;
    float* hbuf = (float*)((char*)d_ws + VOCAB * G4 * sizeof(float));

    build_proj<<<(VOCAB * G4) / 256, 256, 0, stream>>>(emb, w_ih, b_ih, b_hh, proj);

    lstm_rec<<<BATCH, 64, 0, stream>>>(tokens, w_hh, proj, hbuf);

    const int total_pos = BATCH * SEQ;                    // 262144
    const int waves     = total_pos / POS_PER_WAVE;       // 16384
    out_proj<<<waves / 4, 256, 0, stream>>>(hbuf, w_out, b_out, out);
}